// Round 12
// baseline (35.110 us; speedup 1.0000x reference)
//
#include <hip/hip_runtime.h>

// RuleBasedEmbedding round 12: delete the convert node entirely.
//   scatter : 32 blocks; deterministic per-block segment scatter (R11).
//   gemm    : reads f32 rule_mats DIRECTLY (per-XCD class slice = 13 rules
//             x 256KB f32 = 3.3MB -> L2-resident). Per K-step, 512 threads
//             stage the 32x256 f32 slab -> bf16 fragment-order LDS slab,
//             double-buffered (stage ks+1 overlaps MFMA ks, 1 barrier/ks).
//   M is fetched from HBM exactly once (26MB); no 13MB Bfrag write+read.
//
// out[t][e] = sum_d base[token_ids[t]][d] * M[rule[token_ids[t]]][d][e]
// 8192 tokens, D=256, 100 rules.

#define NTOK   8192
#define NRULE  100
#define DIM    256
#define TCH    32                        // tokens per chunk
#define NSEG   32                        // scatter blocks / segments per rule
#define SEGCAP 256                       // tokens per scatter block
#define GSTR   48                        // gemm blocks per XCD class

#define WS_SEGCNT   0                            // [r][b] counts: 3200 ints
#define WS_SEGLIST  (WS_SEGCNT + NRULE * NSEG)   // [r][b][slot]
#define WS_TOTAL_INT (WS_SEGLIST + NRULE * NSEG * SEGCAP)
#define WS_BYTES    ((size_t)WS_TOTAL_INT * 4)   // ~3.3 MB

typedef __attribute__((ext_vector_type(8))) short bf16x8;   // 8 bf16 = 4 VGPR
typedef __attribute__((ext_vector_type(4))) float f32x4;    // MFMA C/D

__device__ __forceinline__ unsigned short f2bf(float f) {
    union { float f; unsigned int u; } c; c.f = f;
    unsigned int u = c.u;
    u = (u + 0x7FFFu + ((u >> 16) & 1u)) >> 16;   // RNE
    return (unsigned short)u;
}

// ---------------- scatter: deterministic per-block segments ----------------
__global__ __launch_bounds__(256)
void scatter_kernel(const int* __restrict__ token_ids,
                    const int* __restrict__ token_rules,
                    int* __restrict__ ws) {
    __shared__ int cur[NRULE];
    const int tid = threadIdx.x, b = blockIdx.x;
    if (tid < NRULE) cur[tid] = 0;
    __syncthreads();
    const int tok = b * SEGCAP + tid;             // 256 tokens per block
    const int id  = token_ids[tok];
    const int r   = token_rules[id];
    const int slot = atomicAdd(&cur[r], 1);       // LDS atomic, in-block
    ws[WS_SEGLIST + (r * NSEG + b) * SEGCAP + slot] = tok;
    __syncthreads();
    if (tid < NRULE) ws[WS_SEGCNT + tid * NSEG + b] = cur[tid];
}

// ---------------- gemm: inline B conversion, double-buffered LDS slab ----------------
__global__ __launch_bounds__(512)
void gemm_kernel(const int* __restrict__ token_ids,
                 const float* __restrict__ base_emb,
                 const float* __restrict__ rule_mats,
                 const int* __restrict__ ws,
                 float* __restrict__ out) {
    const int xcd  = blockIdx.x & 7;
    const int base = blockIdx.x >> 3;               // 0..GSTR-1
    const int tid  = threadIdx.x;
    const int wave = tid >> 6, lane = tid & 63;     // 8 waves

    __shared__ unsigned short sa[8 * 2 * 64 * 8];   // 16 KB A: [ks][tt][lane][e]
    __shared__ unsigned short fb[2][16 * 64 * 8];   // 32 KB B slab, double-buffered
    __shared__ int sst[TCH];
    __shared__ int s_scnt[13][NSEG];
    __shared__ int s_soff[13][NSEG + 1];
    __shared__ int s_tot[13];
    __shared__ int s_choff[14];

    // class tables: rules r = xcd + 8*i, i = 0..12
    if (tid < 13 * NSEG) {
        int i = tid >> 5, b = tid & (NSEG - 1);
        int r = xcd + 8 * i;
        s_scnt[i][b] = (r < NRULE) ? ws[WS_SEGCNT + r * NSEG + b] : 0;
    }
    __syncthreads();
    if (tid < 13) {
        int acc = 0;
        #pragma unroll
        for (int b = 0; b < NSEG; ++b) { s_soff[tid][b] = acc; acc += s_scnt[tid][b]; }
        s_soff[tid][NSEG] = acc;
        s_tot[tid] = acc;
    }
    __syncthreads();
    if (tid == 0) {
        int acc = 0; s_choff[0] = 0;
        #pragma unroll
        for (int i = 0; i < 13; ++i) { acc += (s_tot[i] + TCH - 1) / TCH; s_choff[i + 1] = acc; }
    }
    __syncthreads();
    const int total_ch = s_choff[13];

    // B-stage helper indices (constant per thread):
    //   kk = tid>>4 (k-row within 32-slab), f4 = tid&15 (float4 column group)
    const int kk = tid >> 4, f4 = tid & 15;
    const int e  = kk & 7, khi = (kk >> 3) << 4;    // lane high bits from k

    for (int slot = base; slot < total_ch; slot += GSTR) {
        int i = 0;                                  // largest k with choff[k] <= slot
        #pragma unroll
        for (int k = 1; k < 13; ++k) if (slot >= s_choff[k]) i = k;
        const int r = xcd + 8 * i;
        const int j = slot - s_choff[i];

        __syncthreads();                            // sa/sst/fb safe to overwrite
        if (tid < TCH) {
            int idx = j * TCH + tid;
            int tok = -1;
            if (idx < s_tot[i]) {
                int lo = 0, hi = NSEG - 1;          // largest s with soff[s] <= idx
                while (lo < hi) {
                    int mid = (lo + hi + 1) >> 1;
                    if (s_soff[i][mid] <= idx) lo = mid; else hi = mid - 1;
                }
                tok = ws[WS_SEGLIST + (r * NSEG + lo) * SEGCAP + (idx - s_soff[i][lo])];
            }
            sst[tid] = tok;
        }
        __syncthreads();

        const float4* Mr4 = reinterpret_cast<const float4*>(rule_mats + (size_t)r * DIM * DIM);

        {   // stage A (512 thr) + stage B slab ks=0
            const int s = tid >> 4, q = tid & 15;
            const int pos = sst[s];
            const int tt = s >> 4, lr = s & 15;
            const float4* row4 = nullptr;
            if (pos >= 0)
                row4 = reinterpret_cast<const float4*>(base_emb + (size_t)token_ids[pos] * DIM);
            #pragma unroll
            for (int jj = 0; jj < 4; ++jj) {
                float4 v = row4 ? row4[q * 4 + jj] : make_float4(0.f, 0.f, 0.f, 0.f);
                const int k0 = q * 16 + jj * 4;
                const int ks = k0 >> 5, koff = k0 & 31;
                const int l = lr | ((koff >> 3) << 4);
                const int e0 = koff & 7;
                ushort4 p;
                p.x = f2bf(v.x); p.y = f2bf(v.y); p.z = f2bf(v.z); p.w = f2bf(v.w);
                *reinterpret_cast<ushort4*>(&sa[((ks * 2 + tt) * 64 + l) * 8 + e0]) = p;
            }
            // B slab ks=0: thread reads rows kk, float4 groups f4+16j
            #pragma unroll
            for (int jj = 0; jj < 4; ++jj) {
                const int f4idx = f4 + 16 * jj;
                const float4 v = Mr4[kk * 64 + f4idx];
                const int c0 = f4idx * 4;
                #pragma unroll
                for (int ii = 0; ii < 4; ++ii) {
                    const int col = c0 + ii;
                    const int l = (col & 15) | khi, ct = col >> 4;
                    const float vv = ii == 0 ? v.x : ii == 1 ? v.y : ii == 2 ? v.z : v.w;
                    fb[0][((ct * 64 + l) * 8 + e)] = f2bf(vv);
                }
            }
        }
        __syncthreads();

        f32x4 acc[2][2];
        #pragma unroll
        for (int tt = 0; tt < 2; ++tt)
            #pragma unroll
            for (int ctl = 0; ctl < 2; ++ctl)
                acc[tt][ctl] = (f32x4){0.f, 0.f, 0.f, 0.f};

        const bf16x8* Af = reinterpret_cast<const bf16x8*>(sa);
        const int ct0 = wave * 2;                   // this wave's 2 col-tiles
        int p = 0;

        #pragma unroll
        for (int ks = 0; ks < 8; ++ks) {
            if (ks < 7) {                           // stage next slab into fb[p^1]
                #pragma unroll
                for (int jj = 0; jj < 4; ++jj) {
                    const int f4idx = f4 + 16 * jj;
                    const float4 v = Mr4[((ks + 1) * 32 + kk) * 64 + f4idx];
                    const int c0 = f4idx * 4;
                    #pragma unroll
                    for (int ii = 0; ii < 4; ++ii) {
                        const int col = c0 + ii;
                        const int l = (col & 15) | khi, ct = col >> 4;
                        const float vv = ii == 0 ? v.x : ii == 1 ? v.y : ii == 2 ? v.z : v.w;
                        fb[p ^ 1][((ct * 64 + l) * 8 + e)] = f2bf(vv);
                    }
                }
            }
            const bf16x8* Bf = reinterpret_cast<const bf16x8*>(fb[p]);
            const bf16x8 a0 = Af[(ks * 2 + 0) * 64 + lane];
            const bf16x8 a1 = Af[(ks * 2 + 1) * 64 + lane];
            const bf16x8 b0 = Bf[(ct0 + 0) * 64 + lane];
            const bf16x8 b1 = Bf[(ct0 + 1) * 64 + lane];
            acc[0][0] = __builtin_amdgcn_mfma_f32_16x16x32_bf16(a0, b0, acc[0][0], 0, 0, 0);
            acc[0][1] = __builtin_amdgcn_mfma_f32_16x16x32_bf16(a0, b1, acc[0][1], 0, 0, 0);
            acc[1][0] = __builtin_amdgcn_mfma_f32_16x16x32_bf16(a1, b0, acc[1][0], 0, 0, 0);
            acc[1][1] = __builtin_amdgcn_mfma_f32_16x16x32_bf16(a1, b1, acc[1][1], 0, 0, 0);
            __syncthreads();                        // slab p^1 ready; p reads done
            p ^= 1;
        }

        // D layout: col = lane&15, row = (lane>>4)*4 + reg
        #pragma unroll
        for (int tt = 0; tt < 2; ++tt) {
            #pragma unroll
            for (int reg = 0; reg < 4; ++reg) {
                const int row = tt * 16 + (lane >> 4) * 4 + reg;
                const int pos = sst[row];
                if (pos >= 0) {
                    #pragma unroll
                    for (int ctl = 0; ctl < 2; ++ctl) {
                        const int col = (ct0 + ctl) * 16 + (lane & 15);
                        out[(size_t)pos * DIM + col] = acc[tt][ctl][reg];
                    }
                }
            }
        }
    }
}

// ---------------- fallback (round-1 kernel) if ws too small ----------------
__global__ __launch_bounds__(256, 4)
void rule_embed_fallback(const int* __restrict__ token_ids,
                         const float* __restrict__ base_emb,
                         const float* __restrict__ rule_mats,
                         const int* __restrict__ token_rules,
                         float* __restrict__ out, int n_tokens) {
    const int wave = threadIdx.x >> 6, lane = threadIdx.x & 63;
    const int tok = blockIdx.x * 4 + wave;
    __shared__ float base[4][DIM];
    if (tok < n_tokens) {
        const int tid = token_ids[tok];
        reinterpret_cast<float4*>(base[wave])[lane] =
            reinterpret_cast<const float4*>(base_emb + (size_t)tid * DIM)[lane];
    }
    __syncthreads();
    if (tok >= n_tokens) return;
    const int tid = token_ids[tok];
    const int r = token_rules[tid];
    const float4* M4 = reinterpret_cast<const float4*>(rule_mats + (size_t)r * DIM * DIM);
    float4 acc = make_float4(0.f, 0.f, 0.f, 0.f);
    #pragma unroll 8
    for (int d = 0; d < DIM; ++d) {
        const float b = base[wave][d];
        const float4 m = M4[d * (DIM / 4) + lane];
        acc.x += b * m.x; acc.y += b * m.y; acc.z += b * m.z; acc.w += b * m.w;
    }
    reinterpret_cast<float4*>(out + (size_t)tok * DIM)[lane] = acc;
}

extern "C" void kernel_launch(void* const* d_in, const int* in_sizes, int n_in,
                              void* d_out, int out_size, void* d_ws, size_t ws_size,
                              hipStream_t stream) {
    const int*   token_ids   = (const int*)d_in[0];    // [4, 2048]
    const float* base_emb    = (const float*)d_in[1];  // [32000, 256]
    const float* rule_mats   = (const float*)d_in[2];  // [100, 256, 256]
    const int*   token_rules = (const int*)d_in[3];    // [32000]
    float*       out         = (float*)d_out;          // [4, 2048, 256]

    if (ws_size < WS_BYTES) {
        rule_embed_fallback<<<(NTOK + 3) / 4, 256, 0, stream>>>(
            token_ids, base_emb, rule_mats, token_rules, out, NTOK);
        return;
    }

    int* ws = (int*)d_ws;

    scatter_kernel<<<NSEG, 256, 0, stream>>>(token_ids, token_rules, ws);
    gemm_kernel<<<8 * GSTR, 512, 0, stream>>>(token_ids, base_emb, rule_mats, ws, out);
}

// Round 13
// 21.565 us; speedup vs baseline: 1.6281x; 1.6281x over previous
//
#include <hip/hip_runtime.h>

// RuleBasedEmbedding round 13: R11 (proven 22.0us) + XCD-aligned convert
// placement. R12's inline-conversion regressed (scalar transpose ds_writes);
// reverted.
//   conv_scatter: convert blocks mapped so bid%8 == r%8 -> rule r's Bfrag is
//                 written by the SAME XCD whose gemm class reads it (L2-local
//                 producer->consumer). + 32 deterministic segment-scatter blocks.
//   gemm        : 512-thr (8 waves, 2 col-tiles each); per class (bid&7) sums
//                 segment counts -> chunk prefix; B streamed from XCD-local L2.
//
// out[t][e] = sum_d base[token_ids[t]][d] * M[rule[token_ids[t]]][d][e]
// 8192 tokens, D=256, 100 rules.

#define NTOK   8192
#define NRULE  100
#define DIM    256
#define TCH    32                        // tokens per chunk
#define NSEG   32                        // scatter blocks / segments per rule
#define SEGCAP 256                       // tokens per scatter block
#define GSTR   64                        // gemm blocks per XCD class
#define NCONVS 832                       // convert slots: 8 classes x 13 x 8 ks
#define NBLK_A (NCONVS + NSEG)           // 864

// Bfrag: [r][ks=8][ct=16][lane=64][e=8] bf16 = 13,107,200 B
#define BFRAG_U16   (NRULE * 8 * 16 * 64 * 8)
#define WS_SEGCNT   (BFRAG_U16 / 2)              // [r][b] counts: 3200 ints
#define WS_SEGLIST  (WS_SEGCNT + NRULE * NSEG)   // [r][b][slot]
#define WS_TOTAL_INT (WS_SEGLIST + NRULE * NSEG * SEGCAP)
#define WS_BYTES    ((size_t)WS_TOTAL_INT * 4)   // ~16.4 MB

typedef __attribute__((ext_vector_type(8))) short bf16x8;   // 8 bf16 = 4 VGPR
typedef __attribute__((ext_vector_type(4))) float f32x4;    // MFMA C/D

__device__ __forceinline__ unsigned short f2bf(float f) {
    union { float f; unsigned int u; } c; c.f = f;
    unsigned int u = c.u;
    u = (u + 0x7FFFu + ((u >> 16) & 1u)) >> 16;   // RNE
    return (unsigned short)u;
}

// ---------------- convert (XCD-aligned) + segment-scatter ----------------
__global__ __launch_bounds__(256)
void conv_scatter_kernel(const int* __restrict__ token_ids,
                         const int* __restrict__ token_rules,
                         const float* __restrict__ M,
                         int* __restrict__ ws,
                         unsigned short* __restrict__ bf) {
    const int tid = threadIdx.x;
    const int bid = blockIdx.x;

    if (bid >= NCONVS) {
        // ---- scatter block b: private segments, LDS cursors, plain stores ----
        __shared__ int cur[NRULE];
        const int b = bid - NCONVS;
        if (tid < NRULE) cur[tid] = 0;
        __syncthreads();
        const int tok = b * SEGCAP + tid;             // 256 tokens per block
        const int id  = token_ids[tok];
        const int r   = token_rules[id];
        const int slot = atomicAdd(&cur[r], 1);       // LDS atomic, in-block
        ws[WS_SEGLIST + (r * NSEG + b) * SEGCAP + slot] = tok;
        __syncthreads();
        if (tid < NRULE) ws[WS_SEGCNT + tid * NSEG + b] = cur[tid];
        return;
    }

    // ---- convert slab: bid%8 = class = r%8 (writer XCD == reader XCD) ----
    const int c  = bid & 7;
    const int t  = bid >> 3;                      // 0..103
    const int i  = t >> 3;                        // rule index within class
    const int ks = t & 7;
    const int r  = c + 8 * i;
    if (r >= NRULE) return;                       // empty slots (classes w/ 12 rules)

    __shared__ unsigned short sb[32][DIM];        // 16 KB row-major bf16 slab
    const float4* M4 = reinterpret_cast<const float4*>(M) + ((size_t)r * 256 + ks * 32) * 64;
    #pragma unroll
    for (int j = 0; j < 8; ++j) {
        int idx = j * 256 + tid;                  // 32 rows x 64 float4
        int kl = idx >> 6, c4 = idx & 63;
        float4 v = M4[kl * 64 + c4];
        sb[kl][c4 * 4 + 0] = f2bf(v.x);
        sb[kl][c4 * 4 + 1] = f2bf(v.y);
        sb[kl][c4 * 4 + 2] = f2bf(v.z);
        sb[kl][c4 * 4 + 3] = f2bf(v.w);
    }
    __syncthreads();

    // Bfrag[r][ks][ct][l][e] = M[r][ks*32 + (l>>4)*8 + e][ct*16 + (l&15)]
    uint4* outp = reinterpret_cast<uint4*>(bf) + ((size_t)(r * 8 + ks) * 16) * 64;
    #pragma unroll
    for (int it = 0; it < 4; ++it) {
        int w = it * 256 + tid;                   // 16 ct x 64 lanes
        int ct = w >> 6, l = w & 63;
        int kb = (l >> 4) * 8, cc = ct * 16 + (l & 15);
        unsigned int d0 = sb[kb + 0][cc] | ((unsigned int)sb[kb + 1][cc] << 16);
        unsigned int d1 = sb[kb + 2][cc] | ((unsigned int)sb[kb + 3][cc] << 16);
        unsigned int d2 = sb[kb + 4][cc] | ((unsigned int)sb[kb + 5][cc] << 16);
        unsigned int d3 = sb[kb + 6][cc] | ((unsigned int)sb[kb + 7][cc] << 16);
        outp[ct * 64 + l] = make_uint4(d0, d1, d2, d3);
    }
}

// ---------------- gemm: 8 waves/chunk, 2 col-tiles/wave ----------------
__global__ __launch_bounds__(512)
void gemm_kernel(const int* __restrict__ token_ids,
                 const float* __restrict__ base_emb,
                 const int* __restrict__ ws,
                 const unsigned short* __restrict__ bfrag,
                 float* __restrict__ out) {
    const int xcd  = blockIdx.x & 7;
    const int base = blockIdx.x >> 3;               // 0..GSTR-1
    const int tid  = threadIdx.x;
    const int wave = tid >> 6, lane = tid & 63;     // 8 waves

    __shared__ unsigned short sa[8 * 2 * 64 * 8];   // 16 KB: [ks][tt][lane][e]
    __shared__ int sst[TCH];
    __shared__ int s_scnt[13][NSEG];                // per-rule segment counts
    __shared__ int s_soff[13][NSEG + 1];            // per-rule segment prefix
    __shared__ int s_tot[13];
    __shared__ int s_choff[14];

    // build class tables: rules r = xcd + 8*i, i = 0..12
    if (tid < 13 * NSEG) {
        int i = tid >> 5, b = tid & (NSEG - 1);
        int r = xcd + 8 * i;
        s_scnt[i][b] = (r < NRULE) ? ws[WS_SEGCNT + r * NSEG + b] : 0;
    }
    __syncthreads();
    if (tid < 13) {
        int acc = 0;
        #pragma unroll
        for (int b = 0; b < NSEG; ++b) { s_soff[tid][b] = acc; acc += s_scnt[tid][b]; }
        s_soff[tid][NSEG] = acc;
        s_tot[tid] = acc;
    }
    __syncthreads();
    if (tid == 0) {
        int acc = 0; s_choff[0] = 0;
        #pragma unroll
        for (int i = 0; i < 13; ++i) { acc += (s_tot[i] + TCH - 1) / TCH; s_choff[i + 1] = acc; }
    }
    __syncthreads();
    const int total_ch = s_choff[13];

    for (int slot = base; slot < total_ch; slot += GSTR) {
        int i = 0;                                  // largest k with choff[k] <= slot
        #pragma unroll
        for (int k = 1; k < 13; ++k) if (slot >= s_choff[k]) i = k;
        const int r = xcd + 8 * i;
        const int j = slot - s_choff[i];

        __syncthreads();                            // sa/sst safe to overwrite
        if (tid < TCH) {
            int idx = j * TCH + tid;
            int tok = -1;
            if (idx < s_tot[i]) {
                int lo = 0, hi = NSEG - 1;          // largest s with soff[s] <= idx
                while (lo < hi) {
                    int mid = (lo + hi + 1) >> 1;
                    if (s_soff[i][mid] <= idx) lo = mid; else hi = mid - 1;
                }
                tok = ws[WS_SEGLIST + (r * NSEG + lo) * SEGCAP + (idx - s_soff[i][lo])];
            }
            sst[tid] = tok;
        }
        __syncthreads();

        {   // stage A: 512 thr = (token s 0..31) x (k-sixteenth q 0..15)
            const int s = tid >> 4, q = tid & 15;
            const int pos = sst[s];
            const int tt = s >> 4, lr = s & 15;
            const float4* row4 = nullptr;
            if (pos >= 0)
                row4 = reinterpret_cast<const float4*>(base_emb + (size_t)token_ids[pos] * DIM);
            #pragma unroll
            for (int jj = 0; jj < 4; ++jj) {
                float4 v = row4 ? row4[q * 4 + jj] : make_float4(0.f, 0.f, 0.f, 0.f);
                const int k0 = q * 16 + jj * 4;
                const int ks = k0 >> 5, koff = k0 & 31;
                const int l = lr | ((koff >> 3) << 4);
                const int e0 = koff & 7;             // 0 or 4
                ushort4 p;
                p.x = f2bf(v.x); p.y = f2bf(v.y); p.z = f2bf(v.z); p.w = f2bf(v.w);
                *reinterpret_cast<ushort4*>(&sa[((ks * 2 + tt) * 64 + l) * 8 + e0]) = p;
            }
        }
        __syncthreads();

        f32x4 acc[2][2];
        #pragma unroll
        for (int tt = 0; tt < 2; ++tt)
            #pragma unroll
            for (int ctl = 0; ctl < 2; ++ctl)
                acc[tt][ctl] = (f32x4){0.f, 0.f, 0.f, 0.f};

        const bf16x8* Af = reinterpret_cast<const bf16x8*>(sa);
        const bf16x8* Bf = reinterpret_cast<const bf16x8*>(bfrag) + (size_t)r * 8 * 16 * 64;
        const int ct0 = wave * 2;                   // this wave's 2 col-tiles

        #pragma unroll
        for (int ks = 0; ks < 8; ++ks) {
            const bf16x8 a0 = Af[(ks * 2 + 0) * 64 + lane];
            const bf16x8 a1 = Af[(ks * 2 + 1) * 64 + lane];
            const bf16x8 b0 = Bf[(ks * 16 + ct0 + 0) * 64 + lane];
            const bf16x8 b1 = Bf[(ks * 16 + ct0 + 1) * 64 + lane];
            acc[0][0] = __builtin_amdgcn_mfma_f32_16x16x32_bf16(a0, b0, acc[0][0], 0, 0, 0);
            acc[0][1] = __builtin_amdgcn_mfma_f32_16x16x32_bf16(a0, b1, acc[0][1], 0, 0, 0);
            acc[1][0] = __builtin_amdgcn_mfma_f32_16x16x32_bf16(a1, b0, acc[1][0], 0, 0, 0);
            acc[1][1] = __builtin_amdgcn_mfma_f32_16x16x32_bf16(a1, b1, acc[1][1], 0, 0, 0);
        }

        // D layout: col = lane&15, row = (lane>>4)*4 + reg
        #pragma unroll
        for (int tt = 0; tt < 2; ++tt) {
            #pragma unroll
            for (int reg = 0; reg < 4; ++reg) {
                const int row = tt * 16 + (lane >> 4) * 4 + reg;
                const int pos = sst[row];
                if (pos >= 0) {
                    #pragma unroll
                    for (int ctl = 0; ctl < 2; ++ctl) {
                        const int col = (ct0 + ctl) * 16 + (lane & 15);
                        out[(size_t)pos * DIM + col] = acc[tt][ctl][reg];
                    }
                }
            }
        }
    }
}

// ---------------- fallback (round-1 kernel) if ws too small ----------------
__global__ __launch_bounds__(256, 4)
void rule_embed_fallback(const int* __restrict__ token_ids,
                         const float* __restrict__ base_emb,
                         const float* __restrict__ rule_mats,
                         const int* __restrict__ token_rules,
                         float* __restrict__ out, int n_tokens) {
    const int wave = threadIdx.x >> 6, lane = threadIdx.x & 63;
    const int tok = blockIdx.x * 4 + wave;
    __shared__ float base[4][DIM];
    if (tok < n_tokens) {
        const int tid = token_ids[tok];
        reinterpret_cast<float4*>(base[wave])[lane] =
            reinterpret_cast<const float4*>(base_emb + (size_t)tid * DIM)[lane];
    }
    __syncthreads();
    if (tok >= n_tokens) return;
    const int tid = token_ids[tok];
    const int r = token_rules[tid];
    const float4* M4 = reinterpret_cast<const float4*>(rule_mats + (size_t)r * DIM * DIM);
    float4 acc = make_float4(0.f, 0.f, 0.f, 0.f);
    #pragma unroll 8
    for (int d = 0; d < DIM; ++d) {
        const float b = base[wave][d];
        const float4 m = M4[d * (DIM / 4) + lane];
        acc.x += b * m.x; acc.y += b * m.y; acc.z += b * m.z; acc.w += b * m.w;
    }
    reinterpret_cast<float4*>(out + (size_t)tok * DIM)[lane] = acc;
}

extern "C" void kernel_launch(void* const* d_in, const int* in_sizes, int n_in,
                              void* d_out, int out_size, void* d_ws, size_t ws_size,
                              hipStream_t stream) {
    const int*   token_ids   = (const int*)d_in[0];    // [4, 2048]
    const float* base_emb    = (const float*)d_in[1];  // [32000, 256]
    const float* rule_mats   = (const float*)d_in[2];  // [100, 256, 256]
    const int*   token_rules = (const int*)d_in[3];    // [32000]
    float*       out         = (float*)d_out;          // [4, 2048, 256]

    if (ws_size < WS_BYTES) {
        rule_embed_fallback<<<(NTOK + 3) / 4, 256, 0, stream>>>(
            token_ids, base_emb, rule_mats, token_rules, out, NTOK);
        return;
    }

    int*            ws = (int*)d_ws;
    unsigned short* bf = (unsigned short*)d_ws;

    conv_scatter_kernel<<<NBLK_A, 256, 0, stream>>>(token_ids, token_rules, rule_mats, ws, bf);
    gemm_kernel<<<8 * GSTR, 512, 0, stream>>>(token_ids, base_emb, ws, bf, out);
}